// Round 1
// baseline (366.240 us; speedup 1.0000x reference)
//
#include <hip/hip_runtime.h>

// SSIM (B=16, C=3, H=W=512, fp32) -> scalar mean.
// Separable 11-tap Gaussian: vertical sums per column -> LDS -> horizontal conv + SSIM.
// Partial sums per block in d_ws, final double-precision reduce -> d_out[0].

#define IMG_H 512
#define IMG_W 512
#define N_IMG 48                  // B*C = 16*3
#define WS 11
#define PAD 5
#define TILE_W 256                // output columns per block
#define ROWS_PER_BLOCK 16
#define HALO_W (TILE_W + 2*PAD)   // 266
#define GRID_X N_IMG
#define GRID_Y (IMG_W / TILE_W)                 // 2
#define GRID_Z (IMG_H / ROWS_PER_BLOCK)         // 32
#define N_BLOCKS (GRID_X * GRID_Y * GRID_Z)     // 3072

__global__ __launch_bounds__(256) void ssim_partial_kernel(
    const float* __restrict__ img1,
    const float* __restrict__ img2,
    const float* __restrict__ window,
    float* __restrict__ partial)
{
    __shared__ float vs[5][HALO_W];
    __shared__ float wred[4];

    const int tid = threadIdx.x;
    const int bc  = blockIdx.x;                 // image*channel index 0..47
    const int c0  = blockIdx.y * TILE_W;        // 0 or 256
    const int r0  = blockIdx.z * ROWS_PER_BLOCK;

    // Derive normalized 1-D gaussian g[] from window row 5: w2d[5][j] = g5*g[j],
    // g5 = sqrt(w2d[5][5]).  Reproduces reference weights to ~1e-7 relative.
    float g[WS];
    {
        const float g5  = sqrtf(window[5 * WS + 5]);
        const float inv = 1.0f / g5;
#pragma unroll
        for (int j = 0; j < WS; ++j) g[j] = window[5 * WS + j] * inv;
    }

    const float C1v = 0.01f * 0.01f;
    const float C2v = 0.03f * 0.03f;

    const float* __restrict__ p1 = img1 + (size_t)bc * IMG_H * IMG_W;
    const float* __restrict__ p2 = img2 + (size_t)bc * IMG_H * IMG_W;

    float acc = 0.0f;

    for (int ro = 0; ro < ROWS_PER_BLOCK; ++ro) {
        const int r = r0 + ro;   // output row (uniform across block)

        // ---- vertical gaussian sums for all halo columns ----
        for (int lc = tid; lc < HALO_W; lc += 256) {
            const int gc = c0 - PAD + lc;       // global column
            float s1 = 0.f, s2 = 0.f, s11 = 0.f, s22 = 0.f, s12 = 0.f;
            if (gc >= 0 && gc < IMG_W) {
#pragma unroll
                for (int i = 0; i < WS; ++i) {
                    const int rr = r - PAD + i;  // uniform branch per tap
                    if (rr >= 0 && rr < IMG_H) {
                        const float x1 = p1[rr * IMG_W + gc];
                        const float x2 = p2[rr * IMG_W + gc];
                        const float w  = g[i];
                        s1  += w * x1;
                        s2  += w * x2;
                        s11 += w * x1 * x1;
                        s22 += w * x2 * x2;
                        s12 += w * x1 * x2;
                    }
                }
            }
            vs[0][lc] = s1;  vs[1][lc] = s2;
            vs[2][lc] = s11; vs[3][lc] = s22; vs[4][lc] = s12;
        }
        __syncthreads();

        // ---- horizontal conv + SSIM for output column c0 + tid ----
        {
            float h1 = 0.f, h2 = 0.f, h11 = 0.f, h22 = 0.f, h12 = 0.f;
#pragma unroll
            for (int i = 0; i < WS; ++i) {
                const float w = g[i];
                h1  += w * vs[0][tid + i];
                h2  += w * vs[1][tid + i];
                h11 += w * vs[2][tid + i];
                h22 += w * vs[3][tid + i];
                h12 += w * vs[4][tid + i];
            }
            const float mu1  = h1, mu2 = h2;
            const float mu1s = mu1 * mu1;
            const float mu2s = mu2 * mu2;
            const float mu12 = mu1 * mu2;
            const float s1s  = h11 - mu1s;
            const float s2s  = h22 - mu2s;
            const float s12v = h12 - mu12;
            const float num  = (2.f * mu12 + C1v) * (2.f * s12v + C2v);
            const float den  = (mu1s + mu2s + C1v) * (s1s + s2s + C2v);
            acc += num / den;
        }
        __syncthreads();   // before vs is overwritten next iteration
    }

    // ---- block reduction ----
#pragma unroll
    for (int off = 32; off > 0; off >>= 1)
        acc += __shfl_down(acc, off);
    if ((tid & 63) == 0) wred[tid >> 6] = acc;
    __syncthreads();
    if (tid == 0) {
        const float s = wred[0] + wred[1] + wred[2] + wred[3];
        partial[(blockIdx.z * GRID_Y + blockIdx.y) * GRID_X + blockIdx.x] = s;
    }
}

__global__ __launch_bounds__(256) void ssim_reduce_kernel(
    const float* __restrict__ partial, float* __restrict__ out)
{
    __shared__ double wred[4];
    const int tid = threadIdx.x;
    double s = 0.0;
    for (int i = tid; i < N_BLOCKS; i += 256) s += (double)partial[i];
#pragma unroll
    for (int off = 32; off > 0; off >>= 1)
        s += __shfl_down(s, off);
    if ((tid & 63) == 0) wred[tid >> 6] = s;
    __syncthreads();
    if (tid == 0) {
        const double total = wred[0] + wred[1] + wred[2] + wred[3];
        out[0] = (float)(total / (double)((size_t)N_IMG * IMG_H * IMG_W));
    }
}

extern "C" void kernel_launch(void* const* d_in, const int* in_sizes, int n_in,
                              void* d_out, int out_size, void* d_ws, size_t ws_size,
                              hipStream_t stream) {
    const float* img1   = (const float*)d_in[0];
    const float* img2   = (const float*)d_in[1];
    const float* window = (const float*)d_in[2];
    float* out     = (float*)d_out;
    float* partial = (float*)d_ws;   // N_BLOCKS floats, all written every call

    dim3 grid(GRID_X, GRID_Y, GRID_Z);
    ssim_partial_kernel<<<grid, 256, 0, stream>>>(img1, img2, window, partial);
    ssim_reduce_kernel<<<1, 256, 0, stream>>>(partial, out);
}

// Round 3
// 189.213 us; speedup vs baseline: 1.9356x; 1.9356x over previous
//
#include <hip/hip_runtime.h>

// SSIM (B=16, C=3, H=W=512, fp32) -> scalar mean.
// v3: v2 with ring off-by-one fixed (fresh rows are R+5, R+6 -> slots 10, 11)
// and exact fp32 division in the SSIM formula (no rcp approximation).
//   full-width blocks + per-thread register ring of raw input rows (each
//   global element loaded ~once), separable 11-tap Gaussian:
//   vertical sums from register ring -> LDS (2 rows x 5 planes) ->
//   vectorized horizontal conv (b128 LDS reads, 4 px/thread) + SSIM.
// Per-block partials in d_ws, final double reduce -> d_out[0].

#define IMG_H 512
#define IMG_W 512
#define N_IMG 48                    // B*C
#define WS 11
#define PAD 5
#define CHUNK 32                    // output rows per block
#define NCHUNK (IMG_H / CHUNK)      // 16
#define NBLK (N_IMG * NCHUNK)       // 768
#define RING 12                     // rows held in registers
#define OFF 6                       // LDS data offset (even -> aligned b64 writes)
#define VSW 524                     // OFF + 512 + 5 halo + 1 pad (max idx read 523)

__global__ __launch_bounds__(256) void ssim_partial_kernel(
    const float* __restrict__ img1,
    const float* __restrict__ img2,
    const float* __restrict__ window,
    float* __restrict__ partial)
{
    __shared__ float vs[2][5][VSW];   // [staged row][plane][col]
    __shared__ float wred[4];

    const int tid = threadIdx.x;
    const int bc  = blockIdx.x;              // image*channel 0..47
    const int r0  = blockIdx.y * CHUNK;
    const int col = tid * 2;                 // this thread's 2 owned columns

    // 1-D gaussian from window row 5: w2d[5][j] = g5*g[j], g5 = sqrt(w2d[5][5]).
    float g[WS];
    {
        const float g5  = sqrtf(window[5 * WS + 5]);
        const float inv = 1.0f / g5;
#pragma unroll
        for (int j = 0; j < WS; ++j) g[j] = window[5 * WS + j] * inv;
    }
    const float C1v = 0.01f * 0.01f;
    const float C2v = 0.03f * 0.03f;

    const float* __restrict__ p1 = img1 + (size_t)bc * (IMG_H * IMG_W);
    const float* __restrict__ p2 = img2 + (size_t)bc * (IMG_H * IMG_W);

    // zero entire vs region once; halo/pad columns stay zero forever
    {
        float* vflat = &vs[0][0][0];
        for (int i = tid; i < 2 * 5 * VSW; i += 256) vflat[i] = 0.0f;
    }
    __syncthreads();

    // register ring: raw x1,x2 for the 2 owned columns, RING rows.
    // invariant (after the shift in step with base row R): slot i holds row R-5+i.
    float rx1a[RING], rx1b[RING], rx2a[RING], rx2b[RING];
#pragma unroll
    for (int i = 0; i < RING; ++i) { rx1a[i]=0.f; rx1b[i]=0.f; rx2a[i]=0.f; rx2b[i]=0.f; }

    // warm-up: slots 2..11 <- rows r0-5 .. r0+4 (after first shift -> slots 0..9)
#pragma unroll
    for (int i = 0; i < 10; ++i) {
        const int rr = r0 - PAD + i;
        float a0=0.f, a1=0.f, b0=0.f, b1=0.f;
        if (rr >= 0 && rr < IMG_H) {               // uniform branch
            const float2 u1 = *(const float2*)(p1 + rr * IMG_W + col);
            const float2 u2 = *(const float2*)(p2 + rr * IMG_W + col);
            a0 = u1.x; a1 = u1.y; b0 = u2.x; b1 = u2.y;
        }
        rx1a[2+i] = a0; rx1b[2+i] = a1; rx2a[2+i] = b0; rx2b[2+i] = b1;
    }

    float acc = 0.0f;
    const int rsel = tid >> 7;                 // horizontal phase: staged row 0/1
    const int uu   = (tid & 127) * 4;          // base output col of 4-px unit

    for (int step = 0; step < CHUNK / 2; ++step) {
        const int R = r0 + step * 2;           // output rows R, R+1 this step

        // shift ring by 2
#pragma unroll
        for (int i = 0; i < RING - 2; ++i) {
            rx1a[i] = rx1a[i+2]; rx1b[i] = rx1b[i+2];
            rx2a[i] = rx2a[i+2]; rx2b[i] = rx2b[i+2];
        }
        // load 2 new rows: R+5, R+6 -> slots 10, 11  (slot i = row R-5+i)
#pragma unroll
        for (int j = 0; j < 2; ++j) {
            const int rr = R + PAD + j;
            float a0=0.f, a1=0.f, b0=0.f, b1=0.f;
            if (rr < IMG_H) {                  // rr >= 0 always; uniform branch
                const float2 u1 = *(const float2*)(p1 + rr * IMG_W + col);
                const float2 u2 = *(const float2*)(p2 + rr * IMG_W + col);
                a0 = u1.x; a1 = u1.y; b0 = u2.x; b1 = u2.y;
            }
            rx1a[10+j] = a0; rx1b[10+j] = a1; rx2a[10+j] = b0; rx2b[10+j] = b1;
        }

        // vertical gaussian sums for output rows R (j=0), R+1 (j=1); stage to LDS
#pragma unroll
        for (int j = 0; j < 2; ++j) {
            float v1a=0.f, v2a=0.f, v11a=0.f, v22a=0.f, v12a=0.f;
            float v1b=0.f, v2b=0.f, v11b=0.f, v22b=0.f, v12b=0.f;
#pragma unroll
            for (int i = 0; i < WS; ++i) {
                const float w  = g[i];
                const float x1 = rx1a[i+j], x2 = rx2a[i+j];
                const float t1 = w * x1,    t2 = w * x2;
                v1a += t1; v2a += t2;
                v11a = fmaf(t1, x1, v11a);
                v22a = fmaf(t2, x2, v22a);
                v12a = fmaf(t1, x2, v12a);
                const float y1 = rx1b[i+j], y2 = rx2b[i+j];
                const float s1 = w * y1,    s2 = w * y2;
                v1b += s1; v2b += s2;
                v11b = fmaf(s1, y1, v11b);
                v22b = fmaf(s2, y2, v22b);
                v12b = fmaf(s1, y2, v12b);
            }
            *(float2*)&vs[j][0][OFF + col] = make_float2(v1a,  v1b);
            *(float2*)&vs[j][1][OFF + col] = make_float2(v2a,  v2b);
            *(float2*)&vs[j][2][OFF + col] = make_float2(v11a, v11b);
            *(float2*)&vs[j][3][OFF + col] = make_float2(v22a, v22b);
            *(float2*)&vs[j][4][OFF + col] = make_float2(v12a, v12b);
        }
        __syncthreads();

        // horizontal conv + SSIM: 4 px at row R+rsel, cols uu..uu+3
        float h[5][4];
#pragma unroll
        for (int p = 0; p < 5; ++p) {
            const float4 A = *(const float4*)&vs[rsel][p][uu];
            const float4 B = *(const float4*)&vs[rsel][p][uu + 4];
            const float4 C = *(const float4*)&vs[rsel][p][uu + 8];
            const float4 D = *(const float4*)&vs[rsel][p][uu + 12];
            const float buf[16] = {A.x,A.y,A.z,A.w, B.x,B.y,B.z,B.w,
                                   C.x,C.y,C.z,C.w, D.x,D.y,D.z,D.w};
#pragma unroll
            for (int k = 0; k < 4; ++k) {
                float s = 0.f;
#pragma unroll
                for (int i = 0; i < WS; ++i) s = fmaf(g[i], buf[k + 1 + i], s);
                h[p][k] = s;
            }
        }
#pragma unroll
        for (int k = 0; k < 4; ++k) {
            const float mu1 = h[0][k], mu2 = h[1][k];
            const float mu1s = mu1 * mu1;
            const float mu2s = mu2 * mu2;
            const float mu12 = mu1 * mu2;
            const float sg1  = h[2][k] - mu1s;
            const float sg2  = h[3][k] - mu2s;
            const float sg12 = h[4][k] - mu12;
            const float num  = (2.f * mu12 + C1v) * (2.f * sg12 + C2v);
            const float den  = (mu1s + mu2s + C1v) * (sg1 + sg2 + C2v);
            acc += num / den;                  // exact IEEE div
        }
        __syncthreads();   // before vs is overwritten next step
    }

    // block reduction
#pragma unroll
    for (int off = 32; off > 0; off >>= 1)
        acc += __shfl_down(acc, off);
    if ((tid & 63) == 0) wred[tid >> 6] = acc;
    __syncthreads();
    if (tid == 0) {
        const float s = wred[0] + wred[1] + wred[2] + wred[3];
        partial[blockIdx.y * N_IMG + blockIdx.x] = s;
    }
}

__global__ __launch_bounds__(256) void ssim_reduce_kernel(
    const float* __restrict__ partial, float* __restrict__ out)
{
    __shared__ double wred[4];
    const int tid = threadIdx.x;
    double s = 0.0;
    for (int i = tid; i < NBLK; i += 256) s += (double)partial[i];
#pragma unroll
    for (int off = 32; off > 0; off >>= 1)
        s += __shfl_down(s, off);
    if ((tid & 63) == 0) wred[tid >> 6] = s;
    __syncthreads();
    if (tid == 0) {
        const double total = wred[0] + wred[1] + wred[2] + wred[3];
        out[0] = (float)(total / (double)((size_t)N_IMG * IMG_H * IMG_W));
    }
}

extern "C" void kernel_launch(void* const* d_in, const int* in_sizes, int n_in,
                              void* d_out, int out_size, void* d_ws, size_t ws_size,
                              hipStream_t stream) {
    const float* img1   = (const float*)d_in[0];
    const float* img2   = (const float*)d_in[1];
    const float* window = (const float*)d_in[2];
    float* out     = (float*)d_out;
    float* partial = (float*)d_ws;   // NBLK floats, all written every call

    dim3 grid(N_IMG, NCHUNK);
    ssim_partial_kernel<<<grid, 256, 0, stream>>>(img1, img2, window, partial);
    ssim_reduce_kernel<<<1, 256, 0, stream>>>(partial, out);
}

// Round 4
// 163.922 us; speedup vs baseline: 2.2342x; 1.1543x over previous
//
#include <hip/hip_runtime.h>

// SSIM (B=16, C=3, H=W=512, fp32) -> scalar mean.
// v4: kill LDS bank conflicts (8B lane-stride horizontal reads: thread owns
// cols {2t,2t+1} on BOTH staged rows -> float2 reads, 2-way = free) and
// double the grid (CHUNK=16 -> 1536 blocks) for latency hiding.
// Register ring of raw input rows (each global element loaded ~once),
// separable 11-tap Gaussian: vertical sums -> LDS (2 rows x 5 planes) ->
// horizontal conv from float2 LDS reads + SSIM.
// Per-block partials in d_ws, final double reduce -> d_out[0].

#define IMG_H 512
#define IMG_W 512
#define N_IMG 48                    // B*C
#define WS 11
#define PAD 5
#define CHUNK 16                    // output rows per block
#define NCHUNK (IMG_H / CHUNK)      // 32
#define NBLK (N_IMG * NCHUNK)       // 1536
#define RING 12                     // rows held in registers
#define OFF 6                       // column c stored at element OFF+c
#define VSW 524                     // max element read = 2*255+13 = 523

__global__ __launch_bounds__(256, 4) void ssim_partial_kernel(
    const float* __restrict__ img1,
    const float* __restrict__ img2,
    const float* __restrict__ window,
    float* __restrict__ partial)
{
    __shared__ float vs[2][5][VSW];   // [staged row][plane][element]
    __shared__ float wred[4];

    const int tid = threadIdx.x;
    const int bc  = blockIdx.x;              // image*channel 0..47
    const int r0  = blockIdx.y * CHUNK;
    const int col = tid * 2;                 // owned columns: col, col+1

    // 1-D gaussian from window row 5: w2d[5][j] = g5*g[j], g5 = sqrt(w2d[5][5]).
    float g[WS];
    {
        const float g5  = sqrtf(window[5 * WS + 5]);
        const float inv = 1.0f / g5;
#pragma unroll
        for (int j = 0; j < WS; ++j) g[j] = window[5 * WS + j] * inv;
    }
    const float C1v = 0.01f * 0.01f;
    const float C2v = 0.03f * 0.03f;

    const float* __restrict__ p1 = img1 + (size_t)bc * (IMG_H * IMG_W);
    const float* __restrict__ p2 = img2 + (size_t)bc * (IMG_H * IMG_W);

    // zero entire vs region once; halo/pad elements stay zero forever
    {
        float* vflat = &vs[0][0][0];
        for (int i = tid; i < 2 * 5 * VSW; i += 256) vflat[i] = 0.0f;
    }
    __syncthreads();

    // register ring: raw x1,x2 for the 2 owned columns.
    // invariant (after the shift in step with base row R): slot i holds row R-5+i.
    float rx1a[RING], rx1b[RING], rx2a[RING], rx2b[RING];
#pragma unroll
    for (int i = 0; i < RING; ++i) { rx1a[i]=0.f; rx1b[i]=0.f; rx2a[i]=0.f; rx2b[i]=0.f; }

    // warm-up: slots 2..11 <- rows r0-5 .. r0+4 (after first shift -> slots 0..9)
#pragma unroll
    for (int i = 0; i < 10; ++i) {
        const int rr = r0 - PAD + i;
        float a0=0.f, a1=0.f, b0=0.f, b1=0.f;
        if (rr >= 0 && rr < IMG_H) {               // uniform branch
            const float2 u1 = *(const float2*)(p1 + rr * IMG_W + col);
            const float2 u2 = *(const float2*)(p2 + rr * IMG_W + col);
            a0 = u1.x; a1 = u1.y; b0 = u2.x; b1 = u2.y;
        }
        rx1a[2+i] = a0; rx1b[2+i] = a1; rx2a[2+i] = b0; rx2b[2+i] = b1;
    }

    float acc = 0.0f;

    for (int step = 0; step < CHUNK / 2; ++step) {
        const int R = r0 + step * 2;           // output rows R, R+1 this step

        // shift ring by 2
#pragma unroll
        for (int i = 0; i < RING - 2; ++i) {
            rx1a[i] = rx1a[i+2]; rx1b[i] = rx1b[i+2];
            rx2a[i] = rx2a[i+2]; rx2b[i] = rx2b[i+2];
        }
        // load rows R+5, R+6 -> slots 10, 11 (slot i = row R-5+i)
#pragma unroll
        for (int j = 0; j < 2; ++j) {
            const int rr = R + PAD + j;
            float a0=0.f, a1=0.f, b0=0.f, b1=0.f;
            if (rr < IMG_H) {                  // rr >= 0 always; uniform branch
                const float2 u1 = *(const float2*)(p1 + rr * IMG_W + col);
                const float2 u2 = *(const float2*)(p2 + rr * IMG_W + col);
                a0 = u1.x; a1 = u1.y; b0 = u2.x; b1 = u2.y;
            }
            rx1a[10+j] = a0; rx1b[10+j] = a1; rx2a[10+j] = b0; rx2b[10+j] = b1;
        }

        // vertical gaussian sums for output rows R (j=0), R+1 (j=1); stage to LDS
#pragma unroll
        for (int j = 0; j < 2; ++j) {
            float v1a=0.f, v2a=0.f, v11a=0.f, v22a=0.f, v12a=0.f;
            float v1b=0.f, v2b=0.f, v11b=0.f, v22b=0.f, v12b=0.f;
#pragma unroll
            for (int i = 0; i < WS; ++i) {
                const float w  = g[i];
                const float x1 = rx1a[i+j], x2 = rx2a[i+j];
                const float t1 = w * x1,    t2 = w * x2;
                v1a += t1; v2a += t2;
                v11a = fmaf(t1, x1, v11a);
                v22a = fmaf(t2, x2, v22a);
                v12a = fmaf(t1, x2, v12a);
                const float y1 = rx1b[i+j], y2 = rx2b[i+j];
                const float s1 = w * y1,    s2 = w * y2;
                v1b += s1; v2b += s2;
                v11b = fmaf(s1, y1, v11b);
                v22b = fmaf(s2, y2, v22b);
                v12b = fmaf(s1, y2, v12b);
            }
            *(float2*)&vs[j][0][OFF + col] = make_float2(v1a,  v1b);
            *(float2*)&vs[j][1][OFF + col] = make_float2(v2a,  v2b);
            *(float2*)&vs[j][2][OFF + col] = make_float2(v11a, v11b);
            *(float2*)&vs[j][3][OFF + col] = make_float2(v22a, v22b);
            *(float2*)&vs[j][4][OFF + col] = make_float2(v12a, v12b);
        }
        __syncthreads();

        // horizontal conv + SSIM: 4 px = cols {col, col+1} x rows {R, R+1}.
        // Read elements 2t..2t+13 (= columns col-6..col+7) as 7 float2:
        // 8B lane stride -> 2-way bank aliasing (free), no b128 merging
        // (base alignment provably only 8B).
#pragma unroll
        for (int j = 0; j < 2; ++j) {
            float hv[2][5];
#pragma unroll
            for (int p = 0; p < 5; ++p) {
                const float2* q = (const float2*)&vs[j][p][col];
                const float2 f0=q[0], f1=q[1], f2=q[2], f3=q[3],
                             f4=q[4], f5=q[5], f6=q[6];
                const float b[14] = {f0.x,f0.y,f1.x,f1.y,f2.x,f2.y,f3.x,f3.y,
                                     f4.x,f4.y,f5.x,f5.y,f6.x,f6.y};
                float s0 = 0.f, s1 = 0.f;
#pragma unroll
                for (int i = 0; i < WS; ++i) {
                    s0 = fmaf(g[i], b[i+1], s0);   // px col,   tap i -> b[i+1]
                    s1 = fmaf(g[i], b[i+2], s1);   // px col+1, tap i -> b[i+2]
                }
                hv[0][p] = s0; hv[1][p] = s1;
            }
#pragma unroll
            for (int k = 0; k < 2; ++k) {
                const float mu1 = hv[k][0], mu2 = hv[k][1];
                const float mu1s = mu1 * mu1;
                const float mu2s = mu2 * mu2;
                const float mu12 = mu1 * mu2;
                const float sg1  = hv[k][2] - mu1s;
                const float sg2  = hv[k][3] - mu2s;
                const float sg12 = hv[k][4] - mu12;
                const float num  = (2.f * mu12 + C1v) * (2.f * sg12 + C2v);
                const float den  = (mu1s + mu2s + C1v) * (sg1 + sg2 + C2v);
                acc += num / den;              // exact IEEE div
            }
        }
        __syncthreads();   // before vs is overwritten next step
    }

    // block reduction
#pragma unroll
    for (int off = 32; off > 0; off >>= 1)
        acc += __shfl_down(acc, off);
    if ((tid & 63) == 0) wred[tid >> 6] = acc;
    __syncthreads();
    if (tid == 0) {
        const float s = wred[0] + wred[1] + wred[2] + wred[3];
        partial[blockIdx.y * N_IMG + blockIdx.x] = s;
    }
}

__global__ __launch_bounds__(256) void ssim_reduce_kernel(
    const float* __restrict__ partial, float* __restrict__ out)
{
    __shared__ double wred[4];
    const int tid = threadIdx.x;
    double s = 0.0;
    for (int i = tid; i < NBLK; i += 256) s += (double)partial[i];
#pragma unroll
    for (int off = 32; off > 0; off >>= 1)
        s += __shfl_down(s, off);
    if ((tid & 63) == 0) wred[tid >> 6] = s;
    __syncthreads();
    if (tid == 0) {
        const double total = wred[0] + wred[1] + wred[2] + wred[3];
        out[0] = (float)(total / (double)((size_t)N_IMG * IMG_H * IMG_W));
    }
}

extern "C" void kernel_launch(void* const* d_in, const int* in_sizes, int n_in,
                              void* d_out, int out_size, void* d_ws, size_t ws_size,
                              hipStream_t stream) {
    const float* img1   = (const float*)d_in[0];
    const float* img2   = (const float*)d_in[1];
    const float* window = (const float*)d_in[2];
    float* out     = (float*)d_out;
    float* partial = (float*)d_ws;   // NBLK floats, all written every call

    dim3 grid(N_IMG, NCHUNK);
    ssim_partial_kernel<<<grid, 256, 0, stream>>>(img1, img2, window, partial);
    ssim_reduce_kernel<<<1, 256, 0, stream>>>(partial, out);
}